// Round 6
// baseline (252.189 us; speedup 1.0000x reference)
//
#include <hip/hip_runtime.h>
#include <hip/hip_bf16.h>

typedef __hip_bfloat16 bf16;
typedef __attribute__((ext_vector_type(8))) short short8;
typedef __attribute__((ext_vector_type(4))) float f32x4;

// ---------------- sizes ----------------
#define Bsz   16
#define Tn    512
#define SEG   32
#define CD    256
#define DI    512
#define DS    16
#define DCONV 4
#define BT    (Bsz*Tn)   // 8192
#define NPART 32         // hp partial copies

// ---------------- helpers ----------------
__device__ __forceinline__ float erf_fast(float x) {
  float ax = fabsf(x);
  float t = 1.0f / (1.0f + 0.3275911f * ax);
  float p = t * (0.254829592f + t * (-0.284496736f + t * (1.421413741f +
            t * (-1.453152027f + t * 1.061405429f))));
  float r = 1.0f - p * __expf(-ax * ax);
  return copysignf(r, x);
}
__device__ __forceinline__ float gelu_f(float x) {
  return 0.5f * x * (1.0f + erf_fast(x * 0.7071067811865476f));
}
__device__ __forceinline__ float silu_f(float x) {
  return x / (1.0f + __expf(-x));
}
__device__ __forceinline__ float softplus_f(float x) {
  return fmaxf(x, 0.0f) + __logf(1.0f + __expf(-fabsf(x)));
}
__device__ __forceinline__ float bfu(unsigned short u) {
  return __uint_as_float(((unsigned int)u) << 16);
}
__device__ __forceinline__ unsigned short f2bfu(float x) {
  bf16 h = __float2bfloat16(x);
  return *(unsigned short*)&h;
}
__device__ __forceinline__ float block_sum256(float v, float* red) {
  int tid = threadIdx.x;
  #pragma unroll
  for (int off = 32; off > 0; off >>= 1) v += __shfl_down(v, off, 64);
  __syncthreads();
  if ((tid & 63) == 0) red[tid >> 6] = v;
  __syncthreads();
  return red[0] + red[1] + red[2] + red[3];
}

// ---------------- K0: weight prep + aux path ----------------
// Packed layouts so each MFMA B-load is one contiguous 1KiB wave-load:
//   w_in (1024x256): o = ((nb*8 + k0)*64 + lane)*8 + e
//   wpad (64x512):   o = ((nb*16 + k0)*64 + lane)*8 + e, rows >= 33 zero
// grid 1184: [0,1024) w_in, [1024,1152) wpad, [1152,1184) cpwT; blocks<16 aux.
__global__ __launch_bounds__(256) void prep_kernel(
    const float* __restrict__ aux, const float* __restrict__ apw,
    const float* __restrict__ g, const float* __restrict__ bb,
    const float* __restrict__ in_w, const float* __restrict__ xpw,
    const float* __restrict__ cpw,
    bf16* __restrict__ w_in, bf16* __restrict__ wpad, bf16* __restrict__ cpwT,
    float* __restrict__ haux)
{
  __shared__ float red[4];
  int i = blockIdx.x * 256 + threadIdx.x;
  if (i < 262144) {
    int e = i & 7, lane = (i >> 3) & 63, k0 = (i >> 9) & 7, nb = i >> 12;
    int fr = lane & 15, q = lane >> 4;
    w_in[i] = __float2bfloat16(in_w[(size_t)(nb * 16 + fr) * 256 + k0 * 32 + q * 8 + e]);
  } else if (i < 294912) {
    int o = i - 262144;      // 0..32767
    int e = o & 7, lane = (o >> 3) & 63, k0 = (o >> 9) & 15, nb = o >> 13;
    int fr = lane & 15, q = lane >> 4;
    int row = nb * 16 + fr, k = k0 * 32 + q * 8 + e;
    float v = 0.f;
    if (row < 32)       v = xpw[(1 + row) * 512 + k];
    else if (row == 32) v = xpw[k];
    wpad[o] = __float2bfloat16(v);
  } else {
    int o = i - 294912;      // 0..8191
    int k = o >> 8, j = o & 255;
    cpwT[o] = __float2bfloat16(cpw[j * 32 + k]);
  }
  if (blockIdx.x < 16) {
    int b = blockIdx.x, j = threadIdx.x;
    float acc = 0.f;
    #pragma unroll
    for (int k = 0; k < 14; ++k)
      acc += aux[b * 14 + k] * apw[j * 14 + k];
    float s1 = block_sum256(acc, red);
    float s2 = block_sum256(acc * acc, red);
    float mean = s1 * (1.f / 256.f);
    float var  = s2 * (1.f / 256.f) - mean * mean;
    float xn = (acc - mean) * rsqrtf(var + 1e-5f) * g[j] + bb[j];
    haux[b * 256 + j] = gelu_f(xn);
  }
}

// ---------------- K1: rows + LNs + in_proj MFMA (512 thr, 8 waves) ----------
__global__ __launch_bounds__(512) void row_inproj_kernel(
    const float* __restrict__ cir, const bf16* __restrict__ cpwT,
    const float* __restrict__ cg, const float* __restrict__ cb,
    const float* __restrict__ mg, const float* __restrict__ mb,
    const float* __restrict__ haux, const bf16* __restrict__ w_in,
    bf16* __restrict__ xzbf, float* __restrict__ hp_part)
{
  __shared__ float hps[8][256];
  __shared__ __align__(16) unsigned short xns[16][264];
  int tid = threadIdx.x;
  int wave = tid >> 6, lane = tid & 63;
  int r0 = blockIdx.x * 16 + wave * 2;
  int b = blockIdx.x >> 5;
  int j0 = lane * 4;

  float vj[2][4] = {};
  for (int c = 0; c < 8; ++c) {
    float xk[2][4];
    #pragma unroll
    for (int r4 = 0; r4 < 2; ++r4) {
      float4 xv = ((const float4*)(cir + (size_t)(r0 + r4) * SEG))[c];
      xk[r4][0] = xv.x; xk[r4][1] = xv.y; xk[r4][2] = xv.z; xk[r4][3] = xv.w;
    }
    #pragma unroll
    for (int kk = 0; kk < 4; ++kk) {
      int k = c * 4 + kk;
      uint2 wv = *(const uint2*)((const unsigned short*)cpwT + k * 256 + j0);
      float w0 = __uint_as_float(wv.x << 16);
      float w1 = __uint_as_float(wv.x & 0xffff0000u);
      float w2 = __uint_as_float(wv.y << 16);
      float w3 = __uint_as_float(wv.y & 0xffff0000u);
      #pragma unroll
      for (int r4 = 0; r4 < 2; ++r4) {
        float xv = xk[r4][kk];
        vj[r4][0] += xv * w0; vj[r4][1] += xv * w1;
        vj[r4][2] += xv * w2; vj[r4][3] += xv * w3;
      }
    }
  }
  float s[2], q2[2];
  #pragma unroll
  for (int r4 = 0; r4 < 2; ++r4) {
    s[r4]  = vj[r4][0] + vj[r4][1] + vj[r4][2] + vj[r4][3];
    q2[r4] = vj[r4][0]*vj[r4][0] + vj[r4][1]*vj[r4][1]
           + vj[r4][2]*vj[r4][2] + vj[r4][3]*vj[r4][3];
  }
  #pragma unroll
  for (int off = 32; off > 0; off >>= 1) {
    #pragma unroll
    for (int r4 = 0; r4 < 2; ++r4) {
      s[r4]  += __shfl_xor(s[r4],  off, 64);
      q2[r4] += __shfl_xor(q2[r4], off, 64);
    }
  }
  float4 cgv = *(const float4*)(cg + j0);
  float4 cbv = *(const float4*)(cb + j0);
  float4 hxv = *(const float4*)(haux + b * 256 + j0);
  float hv[2][4];
  float hs[2], hq[2];
  #pragma unroll
  for (int r4 = 0; r4 < 2; ++r4) {
    float mean = s[r4] * (1.f/256.f);
    float var  = q2[r4] * (1.f/256.f) - mean * mean;
    float inv  = rsqrtf(var + 1e-5f);
    float g0 = gelu_f((vj[r4][0] - mean) * inv * cgv.x + cbv.x) + hxv.x;
    float g1 = gelu_f((vj[r4][1] - mean) * inv * cgv.y + cbv.y) + hxv.y;
    float g2 = gelu_f((vj[r4][2] - mean) * inv * cgv.z + cbv.z) + hxv.z;
    float g3 = gelu_f((vj[r4][3] - mean) * inv * cgv.w + cbv.w) + hxv.w;
    hv[r4][0] = g0; hv[r4][1] = g1; hv[r4][2] = g2; hv[r4][3] = g3;
    hs[r4] = g0 + g1 + g2 + g3;
    hq[r4] = g0*g0 + g1*g1 + g2*g2 + g3*g3;
  }
  #pragma unroll
  for (int off = 32; off > 0; off >>= 1) {
    #pragma unroll
    for (int r4 = 0; r4 < 2; ++r4) {
      hs[r4] += __shfl_xor(hs[r4], off, 64);
      hq[r4] += __shfl_xor(hq[r4], off, 64);
    }
  }
  float4 mgv = *(const float4*)(mg + j0);
  float4 mbv = *(const float4*)(mb + j0);
  #pragma unroll
  for (int r4 = 0; r4 < 2; ++r4) {
    float m2  = hs[r4] * (1.f/256.f);
    float v2  = hq[r4] * (1.f/256.f) - m2 * m2;
    float inv2 = rsqrtf(v2 + 1e-5f);
    unsigned int lo = (unsigned int)f2bfu((hv[r4][0] - m2) * inv2 * mgv.x + mbv.x) |
                      ((unsigned int)f2bfu((hv[r4][1] - m2) * inv2 * mgv.y + mbv.y) << 16);
    unsigned int hi = (unsigned int)f2bfu((hv[r4][2] - m2) * inv2 * mgv.z + mbv.z) |
                      ((unsigned int)f2bfu((hv[r4][3] - m2) * inv2 * mgv.w + mbv.w) << 16);
    uint2 pk; pk.x = lo; pk.y = hi;
    *(uint2*)&xns[wave * 2 + r4][j0] = pk;
  }
  #pragma unroll
  for (int q = 0; q < 4; ++q)
    hps[wave][j0 + q] = hv[0][q] + hv[1][q];
  __syncthreads();
  if (tid < 256) {
    int j = tid;
    float part = hps[0][j] + hps[1][j] + hps[2][j] + hps[3][j]
               + hps[4][j] + hps[5][j] + hps[6][j] + hps[7][j];
    hp_part[(size_t)(blockIdx.x & (NPART - 1)) * 4096 + b * 256 + j] =
        part * (1.f / 512.f);
  }
  // ---- in_proj MFMA from LDS: M=16, N=1024 (wave slice 128), K=256 ----
  {
    int fr = lane & 15, quad = lane >> 4;
    int rbase = blockIdx.x * 16;
    const short* Wp = (const short*)w_in;
    unsigned short* xzp = (unsigned short*)xzbf;
    #pragma unroll
    for (int nt = 0; nt < 8; ++nt) {
      int nb = wave * 8 + nt;
      f32x4 acc = {0.f, 0.f, 0.f, 0.f};
      #pragma unroll
      for (int k0 = 0; k0 < 8; ++k0) {
        int ka = k0 * 32 + quad * 8;
        short8 a = *(const short8*)&xns[fr][ka];
        short8 bb8 = *(const short8*)(Wp + (((size_t)nb * 8 + k0) * 64 + lane) * 8);
        acc = __builtin_amdgcn_mfma_f32_16x16x32_bf16(a, bb8, acc, 0, 0, 0);
      }
      int n0 = nb * 16;
      int crow = quad * 4;
      #pragma unroll
      for (int i = 0; i < 4; ++i)
        xzp[(size_t)(rbase + crow + i) * 1024 + n0 + fr] = f2bfu(acc[i]);
    }
  }
}

// ---------------- K2: conv + x_proj MFMA -> ssm (512 thr, 32-t tiles) -------
__global__ __launch_bounds__(512) void conv_xproj_kernel(
    const bf16* __restrict__ xzbf, const bf16* __restrict__ wpad,
    const float* __restrict__ cw, const float* __restrict__ cbv,
    float* __restrict__ ssm)
{
  __shared__ __align__(16) unsigned short xcs[32][520];
  int c = blockIdx.x, b = blockIdx.y;
  int t0 = c * 32;
  int tid = threadIdx.x;
  const unsigned short* xzp = (const unsigned short*)xzbf;

  // ---- Phase A: depthwise conv + silu, 1 d per thread ----
  {
    int d = tid;
    float4 w = *(const float4*)(cw + d * 4);
    float cbd = cbv[d];
    float pa = 0.f, pb = 0.f, pc = 0.f;
    #pragma unroll
    for (int i = 0; i < 3; ++i) {
      int t = t0 - 3 + i;
      float v = (t >= 0) ? bfu(xzp[((size_t)((b << 9) + t)) * 1024 + d]) : 0.f;
      if (i == 0) pa = v; else if (i == 1) pb = v; else pc = v;
    }
    for (int i = 0; i < 32; ++i) {
      int t = t0 + i;
      float x = bfu(xzp[((size_t)((b << 9) + t)) * 1024 + d]);
      float a = cbd + w.x * pa + w.y * pb + w.z * pc + w.w * x;
      pa = pb; pb = pc; pc = x;
      xcs[i][d] = f2bfu(silu_f(a));
    }
  }
  __syncthreads();

  // ---- Phase B: x_proj MFMA from LDS: M=32 (2 halves), N=64, K=512 ----
  {
    int wave = tid >> 6, lane = tid & 63;
    int fr = lane & 15, quad = lane >> 4;
    int mh = wave >> 2;                 // m-half
    int nb = wave & 3;
    int n0 = nb * 16;
    f32x4 acc = {0.f, 0.f, 0.f, 0.f};
    const short* Wp = (const short*)wpad;
    #pragma unroll
    for (int k0 = 0; k0 < 16; ++k0) {
      int ka = k0 * 32 + quad * 8;
      short8 a = *(const short8*)&xcs[mh * 16 + fr][ka];
      short8 b8 = *(const short8*)(Wp + (((size_t)nb * 16 + k0) * 64 + lane) * 8);
      acc = __builtin_amdgcn_mfma_f32_16x16x32_bf16(a, b8, acc, 0, 0, 0);
    }
    int ccol = lane & 15, crow = quad * 4;
    #pragma unroll
    for (int i = 0; i < 4; ++i)
      ssm[((size_t)((b << 9) + t0 + mh * 16 + crow + i)) * 64 + n0 + ccol] = acc[i];
  }
}

// ---------------- K3: full-sequence scan -> ybar (t-mean of gated y) --------
// hp = mean_t(h_cir) + mean_t(y) @ Wout^T  (mean commutes with out_proj), and
// the silu(z) gate distributes into per-(d,s) accumulators, so y[t][d] is
// never materialized. Block (dgrp,b) owns 32 d's, all T=512; thread (d,s)
// carries h in a register across the whole sequence (no chunk stitching).
__global__ __launch_bounds__(512) void scan_full_kernel(
    const bf16* __restrict__ xzbf, const float* __restrict__ ssm,
    const float* __restrict__ cw, const float* __restrict__ cbv,
    const float* __restrict__ dtw, const float* __restrict__ dtb,
    const float* __restrict__ A_log, const float* __restrict__ Dd,
    float* __restrict__ ybar)
{
  __shared__ __align__(16) unsigned short xraw[67][32];
  __shared__ __align__(8)  float BC[64][34];   // [t][2s]=B, [t][2s+1]=C
  __shared__ float dts[64];
  __shared__ __align__(8)  float xcg[64][32][2]; // [t][d][0]=x_conv, [1]=silu(z)

  int dgrp = blockIdx.x, b = blockIdx.y;
  int tid = threadIdx.x;
  int d0 = dgrp * 32;
  int bb = b << 9;
  const unsigned short* xzp = (const unsigned short*)xzbf;

  // scan-role mapping
  int s  = tid & 15;
  int dp = tid >> 4;              // 0..31
  int dS = d0 + dp;
  float wdS = dtw[dS], bdS = dtb[dS];
  float As  = -__expf(A_log[dS * 16 + s]);
  // staging-role mapping
  int d2 = tid & 31;
  int dC = d0 + d2;
  float4 wc = *(const float4*)(cw + dC * 4);
  float cbd = cbv[dC];

  float h = 0.f, yacc = 0.f, xdacc = 0.f;

  for (int tile = 0; tile < 8; ++tile) {
    int t0 = tile * 64;
    __syncthreads();
    // stage x rows t0-3 .. t0+63 (67 x 32 bf16)
    if (tid < 268) {
      int row = tid >> 2, c4 = tid & 3;
      int t = t0 - 3 + row;
      uint4 v = make_uint4(0u, 0u, 0u, 0u);
      if (t >= 0)
        v = *(const uint4*)(xzp + ((size_t)(bb + t)) * 1024 + d0 + c4 * 8);
      *(uint4*)&xraw[row][c4 * 8] = v;
    }
    // stage B/C interleaved + dt
    {
      int r = tid >> 3, l8 = tid & 7;
      const float* srow = ssm + ((size_t)(bb + t0 + r)) * 64;
      float4 v = *(const float4*)(srow + l8 * 4);
      int cc = l8 * 4;
      if (cc < 16) {
        BC[r][cc*2]   = v.x; BC[r][cc*2+2] = v.y;
        BC[r][cc*2+4] = v.z; BC[r][cc*2+6] = v.w;
      } else {
        int c2 = cc - 16;
        BC[r][c2*2+1] = v.x; BC[r][c2*2+3] = v.y;
        BC[r][c2*2+5] = v.z; BC[r][c2*2+7] = v.w;
      }
      if (l8 == 0) dts[r] = srow[32];
    }
    // z gate values into registers (hide latency under staging)
    float zr[4];
    #pragma unroll
    for (int jj = 0; jj < 4; ++jj) {
      int ii = jj * 16 + (tid >> 5);
      zr[jj] = bfu(xzp[((size_t)(bb + t0 + ii)) * 1024 + 512 + dC]);
    }
    __syncthreads();
    // conv + silu (bf16-rounded to match x_proj input path) + gate precompute
    #pragma unroll
    for (int jj = 0; jj < 4; ++jj) {
      int ii = jj * 16 + (tid >> 5);
      float xa = bfu(xraw[ii][d2]);
      float xb = bfu(xraw[ii + 1][d2]);
      float xm = bfu(xraw[ii + 2][d2]);
      float xd = bfu(xraw[ii + 3][d2]);
      float a = cbd + wc.x * xa + wc.y * xb + wc.z * xm + wc.w * xd;
      xcg[ii][d2][0] = bfu(f2bfu(silu_f(a)));
      xcg[ii][d2][1] = silu_f(zr[jj]);
    }
    __syncthreads();
    // serial scan over 64 timesteps
    for (int i = 0; i < 64; ++i) {
      float de = softplus_f(dts[i] * wdS + bdS);
      float2 xg = *(const float2*)&xcg[i][dp][0];
      float2 bc = *(const float2*)&BC[i][s * 2];
      float a = __expf(As * de);
      h = a * h + (de * xg.x) * bc.x;
      yacc  += h * bc.y * xg.y;
      xdacc += xg.x * xg.y;
    }
  }
  // reduce yacc over s (lane bits 0..3)
  yacc += __shfl_xor(yacc, 1, 64);
  yacc += __shfl_xor(yacc, 2, 64);
  yacc += __shfl_xor(yacc, 4, 64);
  yacc += __shfl_xor(yacc, 8, 64);
  if (s == 0)
    ybar[b * 512 + dS] = yacc + Dd[dS] * xdacc;
}

// ---------------- K4: head (hp_part fold + ybar @ Wout^T + MLP) -------------
__global__ __launch_bounds__(256) void head_kernel(
    const float* __restrict__ hp_part, const float* __restrict__ ybar,
    const float* __restrict__ w_out,
    const float* __restrict__ midw, const float* __restrict__ midb,
    const float* __restrict__ mng, const float* __restrict__ mnb,
    const float* __restrict__ bng, const float* __restrict__ bnb,
    const float* __restrict__ f1w, const float* __restrict__ f1b,
    const float* __restrict__ f2w, const float* __restrict__ f2b,
    float* __restrict__ out)
{
  __shared__ float red[4];
  __shared__ __align__(16) float yb[512];
  __shared__ __align__(16) float shp[256];
  __shared__ __align__(16) float sh[256];
  __shared__ __align__(16) float sh2[128];
  int b = blockIdx.x, j = threadIdx.x;
  yb[j]       = ybar[b * 512 + j];
  yb[256 + j] = ybar[b * 512 + 256 + j];
  float hv = 0.f;
  #pragma unroll
  for (int p = 0; p < NPART; ++p)
    hv += hp_part[(size_t)p * 4096 + b * 256 + j];
  __syncthreads();
  // ssm-path contribution: (1/512) * Wout[j] . ybar[b]
  {
    float acc2 = 0.f;
    const float4* wr = (const float4*)(w_out + j * 512);
    const float4* yv = (const float4*)yb;
    #pragma unroll 4
    for (int k = 0; k < 128; ++k) {
      float4 w = wr[k], x = yv[k];
      acc2 += w.x * x.x + w.y * x.y + w.z * x.z + w.w * x.w;
    }
    hv += acc2 * (1.f / 512.f);
  }
  shp[j] = hv;
  __syncthreads();
  float acc = midb[j];
  {
    const float4* mw = (const float4*)(midw + j * 256);
    const float4* sv = (const float4*)shp;
    #pragma unroll 4
    for (int k = 0; k < 64; ++k) {
      float4 w = mw[k], xv = sv[k];
      acc += w.x * xv.x + w.y * xv.y + w.z * xv.z + w.w * xv.w;
    }
  }
  float s1 = block_sum256(acc, red);
  float s2 = block_sum256(acc * acc, red);
  float mean = s1 * (1.f / 256.f);
  float var  = s2 * (1.f / 256.f) - mean * mean;
  float h2 = gelu_f((acc - mean) * rsqrtf(var + 1e-5f) * mng[j] + mnb[j]);
  float hbn = h2 * rsqrtf(1.0f + 1e-5f) * bng[j] + bnb[j];
  sh[j] = hbn;
  __syncthreads();
  if (j < 128) {
    float a2 = f1b[j];
    const float4* fw = (const float4*)(f1w + j * 256);
    const float4* sv = (const float4*)sh;
    #pragma unroll 4
    for (int k = 0; k < 64; ++k) {
      float4 w = fw[k], xv = sv[k];
      a2 += w.x * xv.x + w.y * xv.y + w.z * xv.z + w.w * xv.w;
    }
    sh2[j] = gelu_f(a2);
  }
  __syncthreads();
  if (j == 0) {
    float o = f2b[0];
    const float4* fw = (const float4*)f2w;
    const float4* sv = (const float4*)sh2;
    for (int k = 0; k < 32; ++k) {
      float4 w = fw[k], xv = sv[k];
      o += w.x * xv.x + w.y * xv.y + w.z * xv.z + w.w * xv.w;
    }
    out[b] = o;
  }
}

// ---------------- launch ----------------
extern "C" void kernel_launch(void* const* d_in, const int* in_sizes, int n_in,
                              void* d_out, int out_size, void* d_ws, size_t ws_size,
                              hipStream_t stream)
{
  const float* cir        = (const float*)d_in[0];
  const float* aux        = (const float*)d_in[1];
  const float* cir_proj_w = (const float*)d_in[2];
  const float* cir_norm_g = (const float*)d_in[3];
  const float* cir_norm_b = (const float*)d_in[4];
  const float* aux_proj_w = (const float*)d_in[5];
  const float* aux_norm_g = (const float*)d_in[6];
  const float* aux_norm_b = (const float*)d_in[7];
  const float* m_norm_g   = (const float*)d_in[8];
  const float* m_norm_b   = (const float*)d_in[9];
  const float* in_proj_w  = (const float*)d_in[10];
  const float* conv_w     = (const float*)d_in[11];
  const float* conv_b     = (const float*)d_in[12];
  const float* x_proj_w   = (const float*)d_in[13];
  const float* dt_proj_w  = (const float*)d_in[14];
  const float* dt_proj_b  = (const float*)d_in[15];
  const float* A_log      = (const float*)d_in[16];
  const float* Dd         = (const float*)d_in[17];
  const float* out_proj_w = (const float*)d_in[18];
  const float* mid_w      = (const float*)d_in[19];
  const float* mid_b      = (const float*)d_in[20];
  const float* mid_norm_g = (const float*)d_in[21];
  const float* mid_norm_b = (const float*)d_in[22];
  const float* bn_g       = (const float*)d_in[23];
  const float* bn_b       = (const float*)d_in[24];
  const float* fc1_w      = (const float*)d_in[25];
  const float* fc1_b      = (const float*)d_in[26];
  const float* fc2_w      = (const float*)d_in[27];
  const float* fc2_b      = (const float*)d_in[28];
  float* out = (float*)d_out;

  float* ws      = (float*)d_ws;
  bf16*  xzbf    = (bf16*)ws;                        // BT*1024 bf16 -> 4,194,304 f
  float* ssm     = ws + 4194304;                     // BT*64 f = 524,288
  bf16*  w_inbf  = (bf16*)(ssm + 524288);            // 262,144 bf16 -> 131,072 f
  bf16*  wpadbf  = (bf16*)((float*)w_inbf + 131072); // 32,768 bf16 -> 16,384 f
  bf16*  cpwTbf  = (bf16*)((float*)wpadbf + 16384);  // 8,192 bf16 -> 4,096 f
  float* haux    = (float*)cpwTbf + 4096;            // 4,096 f
  float* hp_part = haux + 4096;                      // NPART*4096 = 131,072 f
  float* ybar    = hp_part + 131072;                 // 8,192 f

  prep_kernel<<<1184, 256, 0, stream>>>(aux, aux_proj_w, aux_norm_g, aux_norm_b,
                                        in_proj_w, x_proj_w, cir_proj_w,
                                        w_inbf, wpadbf, cpwTbf, haux);
  row_inproj_kernel<<<512, 512, 0, stream>>>(cir, cpwTbf, cir_norm_g, cir_norm_b,
                                             m_norm_g, m_norm_b, haux, w_inbf,
                                             xzbf, hp_part);
  conv_xproj_kernel<<<dim3(16, Bsz), 512, 0, stream>>>(xzbf, wpadbf, conv_w, conv_b,
                                                       ssm);
  scan_full_kernel<<<dim3(16, Bsz), 512, 0, stream>>>(xzbf, ssm, conv_w, conv_b,
                                                      dt_proj_w, dt_proj_b,
                                                      A_log, Dd, ybar);
  head_kernel<<<16, 256, 0, stream>>>(hp_part, ybar, out_proj_w,
                                      mid_w, mid_b, mid_norm_g, mid_norm_b,
                                      bn_g, bn_b, fc1_w, fc1_b, fc2_w, fc2_b, out);
}

// Round 7
// 223.352 us; speedup vs baseline: 1.1291x; 1.1291x over previous
//
#include <hip/hip_runtime.h>
#include <hip/hip_bf16.h>

typedef __hip_bfloat16 bf16;
typedef __attribute__((ext_vector_type(8))) short short8;
typedef __attribute__((ext_vector_type(4))) float f32x4;

// ---------------- sizes ----------------
#define Bsz   16
#define Tn    512
#define SEG   32
#define CD    256
#define DI    512
#define DS    16
#define DCONV 4
#define BT    (Bsz*Tn)   // 8192
#define NPART 32         // hp partial copies

// ---------------- helpers ----------------
__device__ __forceinline__ float erf_fast(float x) {
  float ax = fabsf(x);
  float t = 1.0f / (1.0f + 0.3275911f * ax);
  float p = t * (0.254829592f + t * (-0.284496736f + t * (1.421413741f +
            t * (-1.453152027f + t * 1.061405429f))));
  float r = 1.0f - p * __expf(-ax * ax);
  return copysignf(r, x);
}
__device__ __forceinline__ float gelu_f(float x) {
  return 0.5f * x * (1.0f + erf_fast(x * 0.7071067811865476f));
}
__device__ __forceinline__ float silu_f(float x) {
  return x / (1.0f + __expf(-x));
}
__device__ __forceinline__ float softplus_f(float x) {
  return fmaxf(x, 0.0f) + __logf(1.0f + __expf(-fabsf(x)));
}
__device__ __forceinline__ float bfu(unsigned short u) {
  return __uint_as_float(((unsigned int)u) << 16);
}
__device__ __forceinline__ unsigned short f2bfu(float x) {
  bf16 h = __float2bfloat16(x);
  return *(unsigned short*)&h;
}
__device__ __forceinline__ float block_sum256(float v, float* red) {
  int tid = threadIdx.x;
  #pragma unroll
  for (int off = 32; off > 0; off >>= 1) v += __shfl_down(v, off, 64);
  __syncthreads();
  if ((tid & 63) == 0) red[tid >> 6] = v;
  __syncthreads();
  return red[0] + red[1] + red[2] + red[3];
}

// ---------------- K0: weight prep + aux path ----------------
__global__ __launch_bounds__(256) void prep_kernel(
    const float* __restrict__ aux, const float* __restrict__ apw,
    const float* __restrict__ g, const float* __restrict__ bb,
    const float* __restrict__ in_w, const float* __restrict__ xpw,
    const float* __restrict__ cpw,
    bf16* __restrict__ w_in, bf16* __restrict__ wpad, bf16* __restrict__ cpwT,
    float* __restrict__ haux)
{
  __shared__ float red[4];
  int i = blockIdx.x * 256 + threadIdx.x;
  if (i < 262144) {
    int e = i & 7, lane = (i >> 3) & 63, k0 = (i >> 9) & 7, nb = i >> 12;
    int fr = lane & 15, q = lane >> 4;
    w_in[i] = __float2bfloat16(in_w[(size_t)(nb * 16 + fr) * 256 + k0 * 32 + q * 8 + e]);
  } else if (i < 294912) {
    int o = i - 262144;      // 0..32767
    int e = o & 7, lane = (o >> 3) & 63, k0 = (o >> 9) & 15, nb = o >> 13;
    int fr = lane & 15, q = lane >> 4;
    int row = nb * 16 + fr, k = k0 * 32 + q * 8 + e;
    float v = 0.f;
    if (row < 32)       v = xpw[(1 + row) * 512 + k];
    else if (row == 32) v = xpw[k];
    wpad[o] = __float2bfloat16(v);
  } else {
    int o = i - 294912;      // 0..8191
    int k = o >> 8, j = o & 255;
    cpwT[o] = __float2bfloat16(cpw[j * 32 + k]);
  }
  if (blockIdx.x < 16) {
    int b = blockIdx.x, j = threadIdx.x;
    float acc = 0.f;
    #pragma unroll
    for (int k = 0; k < 14; ++k)
      acc += aux[b * 14 + k] * apw[j * 14 + k];
    float s1 = block_sum256(acc, red);
    float s2 = block_sum256(acc * acc, red);
    float mean = s1 * (1.f / 256.f);
    float var  = s2 * (1.f / 256.f) - mean * mean;
    float xn = (acc - mean) * rsqrtf(var + 1e-5f) * g[j] + bb[j];
    haux[b * 256 + j] = gelu_f(xn);
  }
}

// ---------------- K1: rows + LNs + in_proj MFMA (512 thr, 8 waves) ----------
__global__ __launch_bounds__(512) void row_inproj_kernel(
    const float* __restrict__ cir, const bf16* __restrict__ cpwT,
    const float* __restrict__ cg, const float* __restrict__ cb,
    const float* __restrict__ mg, const float* __restrict__ mb,
    const float* __restrict__ haux, const bf16* __restrict__ w_in,
    bf16* __restrict__ xzbf, float* __restrict__ hp_part)
{
  __shared__ float hps[8][256];
  __shared__ __align__(16) unsigned short xns[16][264];
  int tid = threadIdx.x;
  int wave = tid >> 6, lane = tid & 63;
  int r0 = blockIdx.x * 16 + wave * 2;
  int b = blockIdx.x >> 5;
  int j0 = lane * 4;

  float vj[2][4] = {};
  for (int c = 0; c < 8; ++c) {
    float xk[2][4];
    #pragma unroll
    for (int r4 = 0; r4 < 2; ++r4) {
      float4 xv = ((const float4*)(cir + (size_t)(r0 + r4) * SEG))[c];
      xk[r4][0] = xv.x; xk[r4][1] = xv.y; xk[r4][2] = xv.z; xk[r4][3] = xv.w;
    }
    #pragma unroll
    for (int kk = 0; kk < 4; ++kk) {
      int k = c * 4 + kk;
      uint2 wv = *(const uint2*)((const unsigned short*)cpwT + k * 256 + j0);
      float w0 = __uint_as_float(wv.x << 16);
      float w1 = __uint_as_float(wv.x & 0xffff0000u);
      float w2 = __uint_as_float(wv.y << 16);
      float w3 = __uint_as_float(wv.y & 0xffff0000u);
      #pragma unroll
      for (int r4 = 0; r4 < 2; ++r4) {
        float xv = xk[r4][kk];
        vj[r4][0] += xv * w0; vj[r4][1] += xv * w1;
        vj[r4][2] += xv * w2; vj[r4][3] += xv * w3;
      }
    }
  }
  float s[2], q2[2];
  #pragma unroll
  for (int r4 = 0; r4 < 2; ++r4) {
    s[r4]  = vj[r4][0] + vj[r4][1] + vj[r4][2] + vj[r4][3];
    q2[r4] = vj[r4][0]*vj[r4][0] + vj[r4][1]*vj[r4][1]
           + vj[r4][2]*vj[r4][2] + vj[r4][3]*vj[r4][3];
  }
  #pragma unroll
  for (int off = 32; off > 0; off >>= 1) {
    #pragma unroll
    for (int r4 = 0; r4 < 2; ++r4) {
      s[r4]  += __shfl_xor(s[r4],  off, 64);
      q2[r4] += __shfl_xor(q2[r4], off, 64);
    }
  }
  float4 cgv = *(const float4*)(cg + j0);
  float4 cbv = *(const float4*)(cb + j0);
  float4 hxv = *(const float4*)(haux + b * 256 + j0);
  float hv[2][4];
  float hs[2], hq[2];
  #pragma unroll
  for (int r4 = 0; r4 < 2; ++r4) {
    float mean = s[r4] * (1.f/256.f);
    float var  = q2[r4] * (1.f/256.f) - mean * mean;
    float inv  = rsqrtf(var + 1e-5f);
    float g0 = gelu_f((vj[r4][0] - mean) * inv * cgv.x + cbv.x) + hxv.x;
    float g1 = gelu_f((vj[r4][1] - mean) * inv * cgv.y + cbv.y) + hxv.y;
    float g2 = gelu_f((vj[r4][2] - mean) * inv * cgv.z + cbv.z) + hxv.z;
    float g3 = gelu_f((vj[r4][3] - mean) * inv * cgv.w + cbv.w) + hxv.w;
    hv[r4][0] = g0; hv[r4][1] = g1; hv[r4][2] = g2; hv[r4][3] = g3;
    hs[r4] = g0 + g1 + g2 + g3;
    hq[r4] = g0*g0 + g1*g1 + g2*g2 + g3*g3;
  }
  #pragma unroll
  for (int off = 32; off > 0; off >>= 1) {
    #pragma unroll
    for (int r4 = 0; r4 < 2; ++r4) {
      hs[r4] += __shfl_xor(hs[r4], off, 64);
      hq[r4] += __shfl_xor(hq[r4], off, 64);
    }
  }
  float4 mgv = *(const float4*)(mg + j0);
  float4 mbv = *(const float4*)(mb + j0);
  #pragma unroll
  for (int r4 = 0; r4 < 2; ++r4) {
    float m2  = hs[r4] * (1.f/256.f);
    float v2  = hq[r4] * (1.f/256.f) - m2 * m2;
    float inv2 = rsqrtf(v2 + 1e-5f);
    unsigned int lo = (unsigned int)f2bfu((hv[r4][0] - m2) * inv2 * mgv.x + mbv.x) |
                      ((unsigned int)f2bfu((hv[r4][1] - m2) * inv2 * mgv.y + mbv.y) << 16);
    unsigned int hi = (unsigned int)f2bfu((hv[r4][2] - m2) * inv2 * mgv.z + mbv.z) |
                      ((unsigned int)f2bfu((hv[r4][3] - m2) * inv2 * mgv.w + mbv.w) << 16);
    uint2 pk; pk.x = lo; pk.y = hi;
    *(uint2*)&xns[wave * 2 + r4][j0] = pk;
  }
  #pragma unroll
  for (int q = 0; q < 4; ++q)
    hps[wave][j0 + q] = hv[0][q] + hv[1][q];
  __syncthreads();
  if (tid < 256) {
    int j = tid;
    float part = hps[0][j] + hps[1][j] + hps[2][j] + hps[3][j]
               + hps[4][j] + hps[5][j] + hps[6][j] + hps[7][j];
    hp_part[(size_t)(blockIdx.x & (NPART - 1)) * 4096 + b * 256 + j] =
        part * (1.f / 512.f);
  }
  // ---- in_proj MFMA from LDS: M=16, N=1024 (wave slice 128), K=256 ----
  {
    int fr = lane & 15, quad = lane >> 4;
    int rbase = blockIdx.x * 16;
    const short* Wp = (const short*)w_in;
    unsigned short* xzp = (unsigned short*)xzbf;
    #pragma unroll
    for (int nt = 0; nt < 8; ++nt) {
      int nb = wave * 8 + nt;
      f32x4 acc = {0.f, 0.f, 0.f, 0.f};
      #pragma unroll
      for (int k0 = 0; k0 < 8; ++k0) {
        int ka = k0 * 32 + quad * 8;
        short8 a = *(const short8*)&xns[fr][ka];
        short8 bb8 = *(const short8*)(Wp + (((size_t)nb * 8 + k0) * 64 + lane) * 8);
        acc = __builtin_amdgcn_mfma_f32_16x16x32_bf16(a, bb8, acc, 0, 0, 0);
      }
      int n0 = nb * 16;
      int crow = quad * 4;
      #pragma unroll
      for (int i = 0; i < 4; ++i)
        xzp[(size_t)(rbase + crow + i) * 1024 + n0 + fr] = f2bfu(acc[i]);
    }
  }
}

// ---------------- K2: conv + x_proj MFMA -> ssm (LDS-staged x tile) ---------
__global__ __launch_bounds__(512) void conv_xproj_kernel(
    const bf16* __restrict__ xzbf, const bf16* __restrict__ wpad,
    const float* __restrict__ cw, const float* __restrict__ cbv,
    float* __restrict__ ssm)
{
  __shared__ __align__(16) unsigned short xst[35][512];
  __shared__ __align__(16) unsigned short xcs[32][520];
  int c = blockIdx.x, b = blockIdx.y;
  int t0 = c * 32;
  int tid = threadIdx.x;
  const unsigned short* xzp = (const unsigned short*)xzbf;

  // ---- Phase 0: coalesced stage of rows t0-3 .. t0+31 (35 x 512 bf16) ----
  for (int it = tid; it < 2240; it += 512) {
    int row = it >> 6, c8 = it & 63;
    int t = t0 - 3 + row;
    uint4 v = make_uint4(0u, 0u, 0u, 0u);
    if (t >= 0)
      v = *(const uint4*)(xzp + ((size_t)((b << 9) + t)) * 1024 + c8 * 8);
    *(uint4*)&xst[row][c8 * 8] = v;
  }
  __syncthreads();

  // ---- Phase A: depthwise conv + silu from LDS, 1 d per thread ----
  {
    int d = tid;
    float4 w = *(const float4*)(cw + d * 4);
    float cbd = cbv[d];
    float pa = bfu(xst[0][d]), pb = bfu(xst[1][d]), pc = bfu(xst[2][d]);
    #pragma unroll
    for (int i = 0; i < 32; ++i) {
      float x = bfu(xst[3 + i][d]);
      float a = cbd + w.x * pa + w.y * pb + w.z * pc + w.w * x;
      pa = pb; pb = pc; pc = x;
      xcs[i][d] = f2bfu(silu_f(a));
    }
  }
  __syncthreads();

  // ---- Phase B: x_proj MFMA from LDS: M=32 (2 halves), N=64, K=512 ----
  {
    int wave = tid >> 6, lane = tid & 63;
    int fr = lane & 15, quad = lane >> 4;
    int mh = wave >> 2;                 // m-half
    int nb = wave & 3;
    int n0 = nb * 16;
    f32x4 acc = {0.f, 0.f, 0.f, 0.f};
    const short* Wp = (const short*)wpad;
    #pragma unroll
    for (int k0 = 0; k0 < 16; ++k0) {
      int ka = k0 * 32 + quad * 8;
      short8 a = *(const short8*)&xcs[mh * 16 + fr][ka];
      short8 b8 = *(const short8*)(Wp + (((size_t)nb * 16 + k0) * 64 + lane) * 8);
      acc = __builtin_amdgcn_mfma_f32_16x16x32_bf16(a, b8, acc, 0, 0, 0);
    }
    int ccol = lane & 15, crow = quad * 4;
    #pragma unroll
    for (int i = 0; i < 4; ++i)
      ssm[((size_t)((b << 9) + t0 + mh * 16 + crow + i)) * 64 + n0 + ccol] = acc[i];
  }
}

// ---------------- K3: full-sequence scan -> ybar (t-mean of gated y) --------
// Per-tile precompute hoists the 16x-redundant softplus out of the scan:
// cgd[t][d] = {c0 = de*x_conv, gate = silu(z), de}. Inner loop per (d,s):
// 2 LDS reads + 1 exp + 4 mul/fma. D-term sum done in staging role.
__global__ __launch_bounds__(512) void scan_full_kernel(
    const bf16* __restrict__ xzbf, const float* __restrict__ ssm,
    const float* __restrict__ cw, const float* __restrict__ cbv,
    const float* __restrict__ dtw, const float* __restrict__ dtb,
    const float* __restrict__ A_log, const float* __restrict__ Dd,
    float* __restrict__ ybar)
{
  __shared__ __align__(16) unsigned short xraw[67][32];
  __shared__ __align__(8)  float BC[64][34];     // [t][2s]=B, [t][2s+1]=C
  __shared__ float dts[64];
  __shared__ __align__(16) float cgd[64][32][4]; // {c0, gate, de, 0} per (t,d)
  __shared__ float xdp_s[16][32];

  int dgrp = blockIdx.x, b = blockIdx.y;
  int tid = threadIdx.x;
  int d0 = dgrp * 32;
  int bb = b << 9;
  const unsigned short* xzp = (const unsigned short*)xzbf;

  // scan-role mapping
  int s  = tid & 15;
  int dp = tid >> 4;              // 0..31
  int dS = d0 + dp;
  float As  = -__expf(A_log[dS * 16 + s]);
  // staging-role mapping
  int d2 = tid & 31, r16 = tid >> 5;   // r16: 0..15
  int dC = d0 + d2;
  float4 wc = *(const float4*)(cw + dC * 4);
  float cbd = cbv[dC];
  float wdC = dtw[dC], bdC = dtb[dC];

  float h = 0.f, yacc = 0.f, xdp = 0.f;

  for (int tile = 0; tile < 8; ++tile) {
    int t0 = tile * 64;
    __syncthreads();
    // stage x rows t0-3 .. t0+63 (67 x 32 bf16)
    if (tid < 268) {
      int row = tid >> 2, c4 = tid & 3;
      int t = t0 - 3 + row;
      uint4 v = make_uint4(0u, 0u, 0u, 0u);
      if (t >= 0)
        v = *(const uint4*)(xzp + ((size_t)(bb + t)) * 1024 + d0 + c4 * 8);
      *(uint4*)&xraw[row][c4 * 8] = v;
    }
    // stage B/C interleaved + dt
    {
      int r = tid >> 3, l8 = tid & 7;
      const float* srow = ssm + ((size_t)(bb + t0 + r)) * 64;
      float4 v = *(const float4*)(srow + l8 * 4);
      int cc = l8 * 4;
      if (cc < 16) {
        BC[r][cc*2]   = v.x; BC[r][cc*2+2] = v.y;
        BC[r][cc*2+4] = v.z; BC[r][cc*2+6] = v.w;
      } else {
        int c2 = cc - 16;
        BC[r][c2*2+1] = v.x; BC[r][c2*2+3] = v.y;
        BC[r][c2*2+5] = v.z; BC[r][c2*2+7] = v.w;
      }
      if (l8 == 0) dts[r] = srow[32];
    }
    // z gate values into registers (hide latency under staging)
    float zr[4];
    #pragma unroll
    for (int jj = 0; jj < 4; ++jj) {
      int ii = jj * 16 + r16;
      zr[jj] = bfu(xzp[((size_t)(bb + t0 + ii)) * 1024 + 512 + dC]);
    }
    __syncthreads();
    // precompute c0/gate/de per (t,d); accumulate D-term partial
    #pragma unroll
    for (int jj = 0; jj < 4; ++jj) {
      int ii = jj * 16 + r16;
      float xa = bfu(xraw[ii][d2]);
      float xb = bfu(xraw[ii + 1][d2]);
      float xm = bfu(xraw[ii + 2][d2]);
      float xd = bfu(xraw[ii + 3][d2]);
      float a = cbd + wc.x * xa + wc.y * xb + wc.z * xm + wc.w * xd;
      float xc = bfu(f2bfu(silu_f(a)));
      float gt = silu_f(zr[jj]);
      float de = softplus_f(dts[ii] * wdC + bdC);
      xdp += xc * gt;
      float4 pk; pk.x = de * xc; pk.y = gt; pk.z = de; pk.w = 0.f;
      *(float4*)&cgd[ii][d2][0] = pk;
    }
    __syncthreads();
    // serial scan over 64 timesteps: 2 LDS reads + 1 exp + 4 mul/fma
    #pragma unroll 8
    for (int i = 0; i < 64; ++i) {
      float4 cg = *(const float4*)&cgd[i][dp][0];
      float2 bc = *(const float2*)&BC[i][s * 2];
      float a = __expf(As * cg.z);
      h = a * h + cg.x * bc.x;
      yacc += h * (bc.y * cg.y);
    }
  }
  // fold D-term partials (staging layout) and reduce yacc over s
  xdp_s[r16][d2] = xdp;
  yacc += __shfl_xor(yacc, 1, 64);
  yacc += __shfl_xor(yacc, 2, 64);
  yacc += __shfl_xor(yacc, 4, 64);
  yacc += __shfl_xor(yacc, 8, 64);
  __syncthreads();
  if (s == 0) {
    float xds = 0.f;
    #pragma unroll
    for (int k = 0; k < 16; ++k) xds += xdp_s[k][dp];
    ybar[b * 512 + dS] = yacc + Dd[dS] * xds;
  }
}

// ---------------- K4: head (hp_part fold + ybar @ Wout^T + MLP) -------------
__global__ __launch_bounds__(256) void head_kernel(
    const float* __restrict__ hp_part, const float* __restrict__ ybar,
    const float* __restrict__ w_out,
    const float* __restrict__ midw, const float* __restrict__ midb,
    const float* __restrict__ mng, const float* __restrict__ mnb,
    const float* __restrict__ bng, const float* __restrict__ bnb,
    const float* __restrict__ f1w, const float* __restrict__ f1b,
    const float* __restrict__ f2w, const float* __restrict__ f2b,
    float* __restrict__ out)
{
  __shared__ float red[4];
  __shared__ __align__(16) float yb[512];
  __shared__ __align__(16) float shp[256];
  __shared__ __align__(16) float sh[256];
  __shared__ __align__(16) float sh2[128];
  int b = blockIdx.x, j = threadIdx.x;
  yb[j]       = ybar[b * 512 + j];
  yb[256 + j] = ybar[b * 512 + 256 + j];
  float hv = 0.f;
  #pragma unroll
  for (int p = 0; p < NPART; ++p)
    hv += hp_part[(size_t)p * 4096 + b * 256 + j];
  __syncthreads();
  // ssm-path contribution: (1/512) * Wout[j] . ybar[b]
  {
    float acc2 = 0.f;
    const float4* wr = (const float4*)(w_out + j * 512);
    const float4* yv = (const float4*)yb;
    #pragma unroll 4
    for (int k = 0; k < 128; ++k) {
      float4 w = wr[k], x = yv[k];
      acc2 += w.x * x.x + w.y * x.y + w.z * x.z + w.w * x.w;
    }
    hv += acc2 * (1.f / 512.f);
  }
  shp[j] = hv;
  __syncthreads();
  float acc = midb[j];
  {
    const float4* mw = (const float4*)(midw + j * 256);
    const float4* sv = (const float4*)shp;
    #pragma unroll 4
    for (int k = 0; k < 64; ++k) {
      float4 w = mw[k], xv = sv[k];
      acc += w.x * xv.x + w.y * xv.y + w.z * xv.z + w.w * xv.w;
    }
  }
  float s1 = block_sum256(acc, red);
  float s2 = block_sum256(acc * acc, red);
  float mean = s1 * (1.f / 256.f);
  float var  = s2 * (1.f / 256.f) - mean * mean;
  float h2 = gelu_f((acc - mean) * rsqrtf(var + 1e-5f) * mng[j] + mnb[j]);
  float hbn = h2 * rsqrtf(1.0f + 1e-5f) * bng[j] + bnb[j];
  sh[j] = hbn;
  __syncthreads();
  if (j < 128) {
    float a2 = f1b[j];
    const float4* fw = (const float4*)(f1w + j * 256);
    const float4* sv = (const float4*)sh;
    #pragma unroll 4
    for (int k = 0; k < 64; ++k) {
      float4 w = fw[k], xv = sv[k];
      a2 += w.x * xv.x + w.y * xv.y + w.z * xv.z + w.w * xv.w;
    }
    sh2[j] = gelu_f(a2);
  }
  __syncthreads();
  if (j == 0) {
    float o = f2b[0];
    const float4* fw = (const float4*)f2w;
    const float4* sv = (const float4*)sh2;
    for (int k = 0; k < 32; ++k) {
      float4 w = fw[k], xv = sv[k];
      o += w.x * xv.x + w.y * xv.y + w.z * xv.z + w.w * xv.w;
    }
    out[b] = o;
  }
}

// ---------------- launch ----------------
extern "C" void kernel_launch(void* const* d_in, const int* in_sizes, int n_in,
                              void* d_out, int out_size, void* d_ws, size_t ws_size,
                              hipStream_t stream)
{
  const float* cir        = (const float*)d_in[0];
  const float* aux        = (const float*)d_in[1];
  const float* cir_proj_w = (const float*)d_in[2];
  const float* cir_norm_g = (const float*)d_in[3];
  const float* cir_norm_b = (const float*)d_in[4];
  const float* aux_proj_w = (const float*)d_in[5];
  const float* aux_norm_g = (const float*)d_in[6];
  const float* aux_norm_b = (const float*)d_in[7];
  const float* m_norm_g   = (const float*)d_in[8];
  const float* m_norm_b   = (const float*)d_in[9];
  const float* in_proj_w  = (const float*)d_in[10];
  const float* conv_w     = (const float*)d_in[11];
  const float* conv_b     = (const float*)d_in[12];
  const float* x_proj_w   = (const float*)d_in[13];
  const float* dt_proj_w  = (const float*)d_in[14];
  const float* dt_proj_b  = (const float*)d_in[15];
  const float* A_log      = (const float*)d_in[16];
  const float* Dd         = (const float*)d_in[17];
  const float* out_proj_w = (const float*)d_in[18];
  const float* mid_w      = (const float*)d_in[19];
  const float* mid_b      = (const float*)d_in[20];
  const float* mid_norm_g = (const float*)d_in[21];
  const float* mid_norm_b = (const float*)d_in[22];
  const float* bn_g       = (const float*)d_in[23];
  const float* bn_b       = (const float*)d_in[24];
  const float* fc1_w      = (const float*)d_in[25];
  const float* fc1_b      = (const float*)d_in[26];
  const float* fc2_w      = (const float*)d_in[27];
  const float* fc2_b      = (const float*)d_in[28];
  float* out = (float*)d_out;

  float* ws      = (float*)d_ws;
  bf16*  xzbf    = (bf16*)ws;                        // BT*1024 bf16 -> 4,194,304 f
  float* ssm     = ws + 4194304;                     // BT*64 f = 524,288
  bf16*  w_inbf  = (bf16*)(ssm + 524288);            // 262,144 bf16 -> 131,072 f
  bf16*  wpadbf  = (bf16*)((float*)w_inbf + 131072); // 32,768 bf16 -> 16,384 f
  bf16*  cpwTbf  = (bf16*)((float*)wpadbf + 16384);  // 8,192 bf16 -> 4,096 f
  float* haux    = (float*)cpwTbf + 4096;            // 4,096 f
  float* hp_part = haux + 4096;                      // NPART*4096 = 131,072 f
  float* ybar    = hp_part + 131072;                 // 8,192 f

  prep_kernel<<<1184, 256, 0, stream>>>(aux, aux_proj_w, aux_norm_g, aux_norm_b,
                                        in_proj_w, x_proj_w, cir_proj_w,
                                        w_inbf, wpadbf, cpwTbf, haux);
  row_inproj_kernel<<<512, 512, 0, stream>>>(cir, cpwTbf, cir_norm_g, cir_norm_b,
                                             m_norm_g, m_norm_b, haux, w_inbf,
                                             xzbf, hp_part);
  conv_xproj_kernel<<<dim3(16, Bsz), 512, 0, stream>>>(xzbf, wpadbf, conv_w, conv_b,
                                                       ssm);
  scan_full_kernel<<<dim3(16, Bsz), 512, 0, stream>>>(xzbf, ssm, conv_w, conv_b,
                                                      dt_proj_w, dt_proj_b,
                                                      A_log, Dd, ybar);
  head_kernel<<<16, 256, 0, stream>>>(hp_part, ybar, out_proj_w,
                                      mid_w, mid_b, mid_norm_g, mid_norm_b,
                                      bn_g, bn_b, fc1_w, fc1_b, fc2_w, fc2_b, out);
}

// Round 8
// 214.980 us; speedup vs baseline: 1.1731x; 1.0389x over previous
//
#include <hip/hip_runtime.h>
#include <hip/hip_bf16.h>

typedef __hip_bfloat16 bf16;
typedef __attribute__((ext_vector_type(8))) short short8;
typedef __attribute__((ext_vector_type(4))) float f32x4;

// ---------------- sizes ----------------
#define Bsz   16
#define Tn    512
#define SEG   32
#define CD    256
#define DI    512
#define DS    16
#define DCONV 4
#define BT    (Bsz*Tn)   // 8192
#define NPART 32         // hp partial copies

// ---------------- helpers ----------------
__device__ __forceinline__ float erf_fast(float x) {
  float ax = fabsf(x);
  float t = 1.0f / (1.0f + 0.3275911f * ax);
  float p = t * (0.254829592f + t * (-0.284496736f + t * (1.421413741f +
            t * (-1.453152027f + t * 1.061405429f))));
  float r = 1.0f - p * __expf(-ax * ax);
  return copysignf(r, x);
}
__device__ __forceinline__ float gelu_f(float x) {
  return 0.5f * x * (1.0f + erf_fast(x * 0.7071067811865476f));
}
__device__ __forceinline__ float silu_f(float x) {
  return x / (1.0f + __expf(-x));
}
__device__ __forceinline__ float softplus_f(float x) {
  return fmaxf(x, 0.0f) + __logf(1.0f + __expf(-fabsf(x)));
}
__device__ __forceinline__ float bfu(unsigned short u) {
  return __uint_as_float(((unsigned int)u) << 16);
}
__device__ __forceinline__ unsigned short f2bfu(float x) {
  bf16 h = __float2bfloat16(x);
  return *(unsigned short*)&h;
}
__device__ __forceinline__ float block_sum256(float v, float* red) {
  int tid = threadIdx.x;
  #pragma unroll
  for (int off = 32; off > 0; off >>= 1) v += __shfl_down(v, off, 64);
  __syncthreads();
  if ((tid & 63) == 0) red[tid >> 6] = v;
  __syncthreads();
  return red[0] + red[1] + red[2] + red[3];
}

// ---------------- K0: weight prep + aux path ----------------
__global__ __launch_bounds__(256) void prep_kernel(
    const float* __restrict__ aux, const float* __restrict__ apw,
    const float* __restrict__ g, const float* __restrict__ bb,
    const float* __restrict__ in_w, const float* __restrict__ xpw,
    const float* __restrict__ cpw,
    bf16* __restrict__ w_in, bf16* __restrict__ wpad, bf16* __restrict__ cpwT,
    float* __restrict__ haux)
{
  __shared__ float red[4];
  int i = blockIdx.x * 256 + threadIdx.x;
  if (i < 262144) {
    int e = i & 7, lane = (i >> 3) & 63, k0 = (i >> 9) & 7, nb = i >> 12;
    int fr = lane & 15, q = lane >> 4;
    w_in[i] = __float2bfloat16(in_w[(size_t)(nb * 16 + fr) * 256 + k0 * 32 + q * 8 + e]);
  } else if (i < 294912) {
    int o = i - 262144;      // 0..32767
    int e = o & 7, lane = (o >> 3) & 63, k0 = (o >> 9) & 15, nb = o >> 13;
    int fr = lane & 15, q = lane >> 4;
    int row = nb * 16 + fr, k = k0 * 32 + q * 8 + e;
    float v = 0.f;
    if (row < 32)       v = xpw[(1 + row) * 512 + k];
    else if (row == 32) v = xpw[k];
    wpad[o] = __float2bfloat16(v);
  } else {
    int o = i - 294912;      // 0..8191
    int k = o >> 8, j = o & 255;
    cpwT[o] = __float2bfloat16(cpw[j * 32 + k]);
  }
  if (blockIdx.x < 16) {
    int b = blockIdx.x, j = threadIdx.x;
    float acc = 0.f;
    #pragma unroll
    for (int k = 0; k < 14; ++k)
      acc += aux[b * 14 + k] * apw[j * 14 + k];
    float s1 = block_sum256(acc, red);
    float s2 = block_sum256(acc * acc, red);
    float mean = s1 * (1.f / 256.f);
    float var  = s2 * (1.f / 256.f) - mean * mean;
    float xn = (acc - mean) * rsqrtf(var + 1e-5f) * g[j] + bb[j];
    haux[b * 256 + j] = gelu_f(xn);
  }
}

// ---------------- K1: rows + LNs + in_proj MFMA (512 thr, 8 waves) ----------
__global__ __launch_bounds__(512) void row_inproj_kernel(
    const float* __restrict__ cir, const bf16* __restrict__ cpwT,
    const float* __restrict__ cg, const float* __restrict__ cb,
    const float* __restrict__ mg, const float* __restrict__ mb,
    const float* __restrict__ haux, const bf16* __restrict__ w_in,
    bf16* __restrict__ xzbf, float* __restrict__ hp_part)
{
  __shared__ float hps[8][256];
  __shared__ __align__(16) unsigned short xns[16][264];
  int tid = threadIdx.x;
  int wave = tid >> 6, lane = tid & 63;
  int r0 = blockIdx.x * 16 + wave * 2;
  int b = blockIdx.x >> 5;
  int j0 = lane * 4;

  float vj[2][4] = {};
  for (int c = 0; c < 8; ++c) {
    float xk[2][4];
    #pragma unroll
    for (int r4 = 0; r4 < 2; ++r4) {
      float4 xv = ((const float4*)(cir + (size_t)(r0 + r4) * SEG))[c];
      xk[r4][0] = xv.x; xk[r4][1] = xv.y; xk[r4][2] = xv.z; xk[r4][3] = xv.w;
    }
    #pragma unroll
    for (int kk = 0; kk < 4; ++kk) {
      int k = c * 4 + kk;
      uint2 wv = *(const uint2*)((const unsigned short*)cpwT + k * 256 + j0);
      float w0 = __uint_as_float(wv.x << 16);
      float w1 = __uint_as_float(wv.x & 0xffff0000u);
      float w2 = __uint_as_float(wv.y << 16);
      float w3 = __uint_as_float(wv.y & 0xffff0000u);
      #pragma unroll
      for (int r4 = 0; r4 < 2; ++r4) {
        float xv = xk[r4][kk];
        vj[r4][0] += xv * w0; vj[r4][1] += xv * w1;
        vj[r4][2] += xv * w2; vj[r4][3] += xv * w3;
      }
    }
  }
  float s[2], q2[2];
  #pragma unroll
  for (int r4 = 0; r4 < 2; ++r4) {
    s[r4]  = vj[r4][0] + vj[r4][1] + vj[r4][2] + vj[r4][3];
    q2[r4] = vj[r4][0]*vj[r4][0] + vj[r4][1]*vj[r4][1]
           + vj[r4][2]*vj[r4][2] + vj[r4][3]*vj[r4][3];
  }
  #pragma unroll
  for (int off = 32; off > 0; off >>= 1) {
    #pragma unroll
    for (int r4 = 0; r4 < 2; ++r4) {
      s[r4]  += __shfl_xor(s[r4],  off, 64);
      q2[r4] += __shfl_xor(q2[r4], off, 64);
    }
  }
  float4 cgv = *(const float4*)(cg + j0);
  float4 cbv = *(const float4*)(cb + j0);
  float4 hxv = *(const float4*)(haux + b * 256 + j0);
  float hv[2][4];
  float hs[2], hq[2];
  #pragma unroll
  for (int r4 = 0; r4 < 2; ++r4) {
    float mean = s[r4] * (1.f/256.f);
    float var  = q2[r4] * (1.f/256.f) - mean * mean;
    float inv  = rsqrtf(var + 1e-5f);
    float g0 = gelu_f((vj[r4][0] - mean) * inv * cgv.x + cbv.x) + hxv.x;
    float g1 = gelu_f((vj[r4][1] - mean) * inv * cgv.y + cbv.y) + hxv.y;
    float g2 = gelu_f((vj[r4][2] - mean) * inv * cgv.z + cbv.z) + hxv.z;
    float g3 = gelu_f((vj[r4][3] - mean) * inv * cgv.w + cbv.w) + hxv.w;
    hv[r4][0] = g0; hv[r4][1] = g1; hv[r4][2] = g2; hv[r4][3] = g3;
    hs[r4] = g0 + g1 + g2 + g3;
    hq[r4] = g0*g0 + g1*g1 + g2*g2 + g3*g3;
  }
  #pragma unroll
  for (int off = 32; off > 0; off >>= 1) {
    #pragma unroll
    for (int r4 = 0; r4 < 2; ++r4) {
      hs[r4] += __shfl_xor(hs[r4], off, 64);
      hq[r4] += __shfl_xor(hq[r4], off, 64);
    }
  }
  float4 mgv = *(const float4*)(mg + j0);
  float4 mbv = *(const float4*)(mb + j0);
  #pragma unroll
  for (int r4 = 0; r4 < 2; ++r4) {
    float m2  = hs[r4] * (1.f/256.f);
    float v2  = hq[r4] * (1.f/256.f) - m2 * m2;
    float inv2 = rsqrtf(v2 + 1e-5f);
    unsigned int lo = (unsigned int)f2bfu((hv[r4][0] - m2) * inv2 * mgv.x + mbv.x) |
                      ((unsigned int)f2bfu((hv[r4][1] - m2) * inv2 * mgv.y + mbv.y) << 16);
    unsigned int hi = (unsigned int)f2bfu((hv[r4][2] - m2) * inv2 * mgv.z + mbv.z) |
                      ((unsigned int)f2bfu((hv[r4][3] - m2) * inv2 * mgv.w + mbv.w) << 16);
    uint2 pk; pk.x = lo; pk.y = hi;
    *(uint2*)&xns[wave * 2 + r4][j0] = pk;
  }
  #pragma unroll
  for (int q = 0; q < 4; ++q)
    hps[wave][j0 + q] = hv[0][q] + hv[1][q];
  __syncthreads();
  if (tid < 256) {
    int j = tid;
    float part = hps[0][j] + hps[1][j] + hps[2][j] + hps[3][j]
               + hps[4][j] + hps[5][j] + hps[6][j] + hps[7][j];
    hp_part[(size_t)(blockIdx.x & (NPART - 1)) * 4096 + b * 256 + j] =
        part * (1.f / 512.f);
  }
  // ---- in_proj MFMA from LDS: M=16, N=1024 (wave slice 128), K=256 ----
  {
    int fr = lane & 15, quad = lane >> 4;
    int rbase = blockIdx.x * 16;
    const short* Wp = (const short*)w_in;
    unsigned short* xzp = (unsigned short*)xzbf;
    #pragma unroll
    for (int nt = 0; nt < 8; ++nt) {
      int nb = wave * 8 + nt;
      f32x4 acc = {0.f, 0.f, 0.f, 0.f};
      #pragma unroll
      for (int k0 = 0; k0 < 8; ++k0) {
        int ka = k0 * 32 + quad * 8;
        short8 a = *(const short8*)&xns[fr][ka];
        short8 bb8 = *(const short8*)(Wp + (((size_t)nb * 8 + k0) * 64 + lane) * 8);
        acc = __builtin_amdgcn_mfma_f32_16x16x32_bf16(a, bb8, acc, 0, 0, 0);
      }
      int n0 = nb * 16;
      int crow = quad * 4;
      #pragma unroll
      for (int i = 0; i < 4; ++i)
        xzp[(size_t)(rbase + crow + i) * 1024 + n0 + fr] = f2bfu(acc[i]);
    }
  }
}

// ---------------- K2: conv + x_proj MFMA -> ssm (LDS-staged x tile) ---------
__global__ __launch_bounds__(512) void conv_xproj_kernel(
    const bf16* __restrict__ xzbf, const bf16* __restrict__ wpad,
    const float* __restrict__ cw, const float* __restrict__ cbv,
    float* __restrict__ ssm)
{
  __shared__ __align__(16) unsigned short xst[35][512];
  __shared__ __align__(16) unsigned short xcs[32][520];
  int c = blockIdx.x, b = blockIdx.y;
  int t0 = c * 32;
  int tid = threadIdx.x;
  const unsigned short* xzp = (const unsigned short*)xzbf;

  // ---- Phase 0: coalesced stage of rows t0-3 .. t0+31 (35 x 512 bf16) ----
  for (int it = tid; it < 2240; it += 512) {
    int row = it >> 6, c8 = it & 63;
    int t = t0 - 3 + row;
    uint4 v = make_uint4(0u, 0u, 0u, 0u);
    if (t >= 0)
      v = *(const uint4*)(xzp + ((size_t)((b << 9) + t)) * 1024 + c8 * 8);
    *(uint4*)&xst[row][c8 * 8] = v;
  }
  __syncthreads();

  // ---- Phase A: depthwise conv + silu from LDS, 1 d per thread ----
  {
    int d = tid;
    float4 w = *(const float4*)(cw + d * 4);
    float cbd = cbv[d];
    float pa = bfu(xst[0][d]), pb = bfu(xst[1][d]), pc = bfu(xst[2][d]);
    #pragma unroll
    for (int i = 0; i < 32; ++i) {
      float x = bfu(xst[3 + i][d]);
      float a = cbd + w.x * pa + w.y * pb + w.z * pc + w.w * x;
      pa = pb; pb = pc; pc = x;
      xcs[i][d] = f2bfu(silu_f(a));
    }
  }
  __syncthreads();

  // ---- Phase B: x_proj MFMA from LDS: M=32 (2 halves), N=64, K=512 ----
  {
    int wave = tid >> 6, lane = tid & 63;
    int fr = lane & 15, quad = lane >> 4;
    int mh = wave >> 2;                 // m-half
    int nb = wave & 3;
    int n0 = nb * 16;
    f32x4 acc = {0.f, 0.f, 0.f, 0.f};
    const short* Wp = (const short*)wpad;
    #pragma unroll
    for (int k0 = 0; k0 < 16; ++k0) {
      int ka = k0 * 32 + quad * 8;
      short8 a = *(const short8*)&xcs[mh * 16 + fr][ka];
      short8 b8 = *(const short8*)(Wp + (((size_t)nb * 16 + k0) * 64 + lane) * 8);
      acc = __builtin_amdgcn_mfma_f32_16x16x32_bf16(a, b8, acc, 0, 0, 0);
    }
    int ccol = lane & 15, crow = quad * 4;
    #pragma unroll
    for (int i = 0; i < 4; ++i)
      ssm[((size_t)((b << 9) + t0 + mh * 16 + crow + i)) * 64 + n0 + ccol] = acc[i];
  }
}

// ---------------- K3: full-sequence scan, 2 half-chains per (d,s) -----------
// 1024 thr: (s, d, half). Half B runs with zero-init local state and tracks
// P = prod(a), K = sum(P * C*g); true contribution = yaccB + h_endA * K.
// 16 waves/CU (2x TLP vs 512-thr version), 256-step serial span per thread.
__global__ __launch_bounds__(1024) void scan_full_kernel(
    const bf16* __restrict__ xzbf, const float* __restrict__ ssm,
    const float* __restrict__ cw, const float* __restrict__ cbv,
    const float* __restrict__ dtw, const float* __restrict__ dtb,
    const float* __restrict__ A_log, const float* __restrict__ Dd,
    float* __restrict__ ybar)
{
  __shared__ __align__(16) unsigned short xraw[2][35][32];
  __shared__ __align__(16) unsigned short zraw[2][32][32];
  __shared__ __align__(8)  float BC[2][32][34];   // [t][2s]=B, [t][2s+1]=C
  __shared__ float dts[2][32];
  __shared__ __align__(16) float cgd[2][32][32][4]; // {c0, gate, de, 0}
  __shared__ float xdp_s[32][32];
  __shared__ float hendA[32][16];
  __shared__ float ybh[2][32];

  int dgrp = blockIdx.x, b = blockIdx.y;
  int tid = threadIdx.x;
  int d0 = dgrp * 32;
  int bb = b << 9;
  const unsigned short* xzp = (const unsigned short*)xzbf;

  // scan-role mapping
  int s  = tid & 15;
  int dp = (tid >> 4) & 31;
  int qh = tid >> 9;               // half: 0 -> t in [0,256), 1 -> [256,512)
  int dS = d0 + dp;
  float As  = -__expf(A_log[dS * 16 + s]);
  // precompute-role mapping
  int d2 = tid & 31, r32 = (tid >> 5) & 31;
  int dC = d0 + d2;
  float4 wc = *(const float4*)(cw + dC * 4);
  float cbd = cbv[dC];
  float wdC = dtw[dC], bdC = dtb[dC];

  float h = 0.f, yacc = 0.f, P = 1.f, K = 0.f, xdp = 0.f;

  for (int p = 0; p < 8; ++p) {
    __syncthreads();
    // ---- stage both halves' 32-t tiles ----
    if (tid < 512) {
      for (int it = tid; it < 536; it += 512) {
        int q = it >= 268;
        int e = it - (q ? 268 : 0);
        int t0q = q * 256 + p * 32;
        if (e < 140) {
          int row = e >> 2, c4 = e & 3;
          int t = t0q - 3 + row;
          uint4 v = make_uint4(0u, 0u, 0u, 0u);
          if (t >= 0)
            v = *(const uint4*)(xzp + (size_t)(bb + t) * 1024 + d0 + c4 * 8);
          *(uint4*)&xraw[q][row][c4 * 8] = v;
        } else {
          int e2 = e - 140;
          int row = e2 >> 2, c4 = e2 & 3;
          uint4 v = *(const uint4*)(xzp + (size_t)(bb + t0q + row) * 1024 + 512 + d0 + c4 * 8);
          *(uint4*)&zraw[q][row][c4 * 8] = v;
        }
      }
    } else {
      int t2 = tid - 512;
      int q = t2 >> 8;
      int r = (t2 >> 3) & 31, l8 = t2 & 7;
      int t0q = q * 256 + p * 32;
      const float* srow = ssm + (size_t)(bb + t0q + r) * 64;
      float4 v = *(const float4*)(srow + l8 * 4);
      int cc = l8 * 4;
      if (cc < 16) {
        BC[q][r][cc*2]   = v.x; BC[q][r][cc*2+2] = v.y;
        BC[q][r][cc*2+4] = v.z; BC[q][r][cc*2+6] = v.w;
      } else {
        int c2 = cc - 16;
        BC[q][r][c2*2+1] = v.x; BC[q][r][c2*2+3] = v.y;
        BC[q][r][c2*2+5] = v.z; BC[q][r][c2*2+7] = v.w;
      }
      if (l8 == 0) dts[q][r] = srow[32];
    }
    __syncthreads();
    // ---- precompute c0/gate/de per (t,d), both halves; D-term partial ----
    #pragma unroll
    for (int q = 0; q < 2; ++q) {
      int ii = r32;
      float xa = bfu(xraw[q][ii][d2]);
      float xb = bfu(xraw[q][ii + 1][d2]);
      float xm = bfu(xraw[q][ii + 2][d2]);
      float xd = bfu(xraw[q][ii + 3][d2]);
      float a = cbd + wc.x * xa + wc.y * xb + wc.z * xm + wc.w * xd;
      float xc = bfu(f2bfu(silu_f(a)));
      float gt = silu_f(bfu(zraw[q][ii][d2]));
      float de = softplus_f(dts[q][ii] * wdC + bdC);
      xdp += xc * gt;
      float4 pk; pk.x = de * xc; pk.y = gt; pk.z = de; pk.w = 0.f;
      *(float4*)&cgd[q][ii][d2][0] = pk;
    }
    __syncthreads();
    // ---- scan 32 steps on own half ----
    #pragma unroll
    for (int i = 0; i < 32; ++i) {
      float4 cg = *(const float4*)&cgd[qh][i][dp][0];
      float2 bc = *(const float2*)&BC[qh][i][s * 2];
      float a = __expf(As * cg.z);
      h = a * h + cg.x * bc.x;
      float w = bc.y * cg.y;
      yacc += h * w;
      if (qh) { P *= a; K += P * w; }   // wave-uniform branch
    }
  }
  // ---- combine halves + reduce ----
  xdp_s[r32][d2] = xdp;
  if (qh == 0) hendA[dp][s] = h;
  __syncthreads();
  if (qh == 1) yacc += hendA[dp][s] * K;
  yacc += __shfl_xor(yacc, 1, 64);
  yacc += __shfl_xor(yacc, 2, 64);
  yacc += __shfl_xor(yacc, 4, 64);
  yacc += __shfl_xor(yacc, 8, 64);
  if (s == 0) ybh[qh][dp] = yacc;
  __syncthreads();
  if (qh == 0 && s == 0) {
    float xds = 0.f;
    #pragma unroll
    for (int k = 0; k < 32; ++k) xds += xdp_s[k][dp];
    ybar[b * 512 + dS] = ybh[0][dp] + ybh[1][dp] + Dd[dS] * xds;
  }
}

// ---------------- K4: head (hp_part fold + ybar @ Wout^T + MLP) -------------
__global__ __launch_bounds__(256) void head_kernel(
    const float* __restrict__ hp_part, const float* __restrict__ ybar,
    const float* __restrict__ w_out,
    const float* __restrict__ midw, const float* __restrict__ midb,
    const float* __restrict__ mng, const float* __restrict__ mnb,
    const float* __restrict__ bng, const float* __restrict__ bnb,
    const float* __restrict__ f1w, const float* __restrict__ f1b,
    const float* __restrict__ f2w, const float* __restrict__ f2b,
    float* __restrict__ out)
{
  __shared__ float red[4];
  __shared__ __align__(16) float yb[512];
  __shared__ __align__(16) float shp[256];
  __shared__ __align__(16) float sh[256];
  __shared__ __align__(16) float sh2[128];
  int b = blockIdx.x, j = threadIdx.x;
  yb[j]       = ybar[b * 512 + j];
  yb[256 + j] = ybar[b * 512 + 256 + j];
  float hv = 0.f;
  #pragma unroll
  for (int p = 0; p < NPART; ++p)
    hv += hp_part[(size_t)p * 4096 + b * 256 + j];
  __syncthreads();
  // ssm-path contribution: (1/512) * Wout[j] . ybar[b]
  {
    float acc2 = 0.f;
    const float4* wr = (const float4*)(w_out + j * 512);
    const float4* yv = (const float4*)yb;
    #pragma unroll 4
    for (int k = 0; k < 128; ++k) {
      float4 w = wr[k], x = yv[k];
      acc2 += w.x * x.x + w.y * x.y + w.z * x.z + w.w * x.w;
    }
    hv += acc2 * (1.f / 512.f);
  }
  shp[j] = hv;
  __syncthreads();
  float acc = midb[j];
  {
    const float4* mw = (const float4*)(midw + j * 256);
    const float4* sv = (const float4*)shp;
    #pragma unroll 4
    for (int k = 0; k < 64; ++k) {
      float4 w = mw[k], xv = sv[k];
      acc += w.x * xv.x + w.y * xv.y + w.z * xv.z + w.w * xv.w;
    }
  }
  float s1 = block_sum256(acc, red);
  float s2 = block_sum256(acc * acc, red);
  float mean = s1 * (1.f / 256.f);
  float var  = s2 * (1.f / 256.f) - mean * mean;
  float h2 = gelu_f((acc - mean) * rsqrtf(var + 1e-5f) * mng[j] + mnb[j]);
  float hbn = h2 * rsqrtf(1.0f + 1e-5f) * bng[j] + bnb[j];
  sh[j] = hbn;
  __syncthreads();
  if (j < 128) {
    float a2 = f1b[j];
    const float4* fw = (const float4*)(f1w + j * 256);
    const float4* sv = (const float4*)sh;
    #pragma unroll 4
    for (int k = 0; k < 64; ++k) {
      float4 w = fw[k], xv = sv[k];
      a2 += w.x * xv.x + w.y * xv.y + w.z * xv.z + w.w * xv.w;
    }
    sh2[j] = gelu_f(a2);
  }
  __syncthreads();
  if (j == 0) {
    float o = f2b[0];
    const float4* fw = (const float4*)f2w;
    const float4* sv = (const float4*)sh2;
    for (int k = 0; k < 32; ++k) {
      float4 w = fw[k], xv = sv[k];
      o += w.x * xv.x + w.y * xv.y + w.z * xv.z + w.w * xv.w;
    }
    out[b] = o;
  }
}

// ---------------- launch ----------------
extern "C" void kernel_launch(void* const* d_in, const int* in_sizes, int n_in,
                              void* d_out, int out_size, void* d_ws, size_t ws_size,
                              hipStream_t stream)
{
  const float* cir        = (const float*)d_in[0];
  const float* aux        = (const float*)d_in[1];
  const float* cir_proj_w = (const float*)d_in[2];
  const float* cir_norm_g = (const float*)d_in[3];
  const float* cir_norm_b = (const float*)d_in[4];
  const float* aux_proj_w = (const float*)d_in[5];
  const float* aux_norm_g = (const float*)d_in[6];
  const float* aux_norm_b = (const float*)d_in[7];
  const float* m_norm_g   = (const float*)d_in[8];
  const float* m_norm_b   = (const float*)d_in[9];
  const float* in_proj_w  = (const float*)d_in[10];
  const float* conv_w     = (const float*)d_in[11];
  const float* conv_b     = (const float*)d_in[12];
  const float* x_proj_w   = (const float*)d_in[13];
  const float* dt_proj_w  = (const float*)d_in[14];
  const float* dt_proj_b  = (const float*)d_in[15];
  const float* A_log      = (const float*)d_in[16];
  const float* Dd         = (const float*)d_in[17];
  const float* out_proj_w = (const float*)d_in[18];
  const float* mid_w      = (const float*)d_in[19];
  const float* mid_b      = (const float*)d_in[20];
  const float* mid_norm_g = (const float*)d_in[21];
  const float* mid_norm_b = (const float*)d_in[22];
  const float* bn_g       = (const float*)d_in[23];
  const float* bn_b       = (const float*)d_in[24];
  const float* fc1_w      = (const float*)d_in[25];
  const float* fc1_b      = (const float*)d_in[26];
  const float* fc2_w      = (const float*)d_in[27];
  const float* fc2_b      = (const float*)d_in[28];
  float* out = (float*)d_out;

  float* ws      = (float*)d_ws;
  bf16*  xzbf    = (bf16*)ws;                        // BT*1024 bf16 -> 4,194,304 f
  float* ssm     = ws + 4194304;                     // BT*64 f = 524,288
  bf16*  w_inbf  = (bf16*)(ssm + 524288);            // 262,144 bf16 -> 131,072 f
  bf16*  wpadbf  = (bf16*)((float*)w_inbf + 131072); // 32,768 bf16 -> 16,384 f
  bf16*  cpwTbf  = (bf16*)((float*)wpadbf + 16384);  // 8,192 bf16 -> 4,096 f
  float* haux    = (float*)cpwTbf + 4096;            // 4,096 f
  float* hp_part = haux + 4096;                      // NPART*4096 = 131,072 f
  float* ybar    = hp_part + 131072;                 // 8,192 f

  prep_kernel<<<1184, 256, 0, stream>>>(aux, aux_proj_w, aux_norm_g, aux_norm_b,
                                        in_proj_w, x_proj_w, cir_proj_w,
                                        w_inbf, wpadbf, cpwTbf, haux);
  row_inproj_kernel<<<512, 512, 0, stream>>>(cir, cpwTbf, cir_norm_g, cir_norm_b,
                                             m_norm_g, m_norm_b, haux, w_inbf,
                                             xzbf, hp_part);
  conv_xproj_kernel<<<dim3(16, Bsz), 512, 0, stream>>>(xzbf, wpadbf, conv_w, conv_b,
                                                       ssm);
  scan_full_kernel<<<dim3(16, Bsz), 1024, 0, stream>>>(xzbf, ssm, conv_w, conv_b,
                                                       dt_proj_w, dt_proj_b,
                                                       A_log, Dd, ybar);
  head_kernel<<<16, 256, 0, stream>>>(hp_part, ybar, out_proj_w,
                                      mid_w, mid_b, mid_norm_g, mid_norm_b,
                                      bn_g, bn_b, fc1_w, fc1_b, fc2_w, fc2_b, out);
}